// Round 1
// baseline (1255.420 us; speedup 1.0000x reference)
//
#include <hip/hip_runtime.h>

// Shapes (fixed for this problem)
#define D_DIM 1024
#define S_DIM 2048
#define B_DIM 4
#define M_DIM 4096
#define NTOK  8192   // B*S

typedef unsigned short u16;
typedef __attribute__((ext_vector_type(8))) short short8;  // 8 bf16 (guide-verified frag type)
typedef __attribute__((ext_vector_type(4))) float fx4;

static __device__ __forceinline__ float b2f(u16 u) {
  union { unsigned int i; float f; } v; v.i = ((unsigned int)u) << 16; return v.f;
}
static __device__ __forceinline__ u16 f2b(float f) {
  union { float f; unsigned int i; } v; v.f = f;
  unsigned int r = v.i + 0x7fffu + ((v.i >> 16) & 1u); // RNE
  return (u16)(r >> 16);
}
// async global->LDS DMA, 16B per lane
static __device__ __forceinline__ void async16(u16* lds, const u16* g) {
  __builtin_amdgcn_global_load_lds(
      (__attribute__((address_space(1))) void*)(u16*)g,
      (__attribute__((address_space(3))) void*)lds, 16, 0, 0);
}

#define FENCE asm volatile("" ::: "memory")
#define BARR  do { FENCE; __builtin_amdgcn_s_barrier(); FENCE; } while (0)

// ---------------- canary: prefill fp32 output with 1.0 (diagnostic) ----------------
__global__ void canary_kernel(float* __restrict__ out) {
  const long i = ((long)blockIdx.x * 256 + threadIdx.x) * 4;
  float4 v = {1.0f, 1.0f, 1.0f, 1.0f};
  *(float4*)(out + i) = v;
}

// ---------------- embedding gather + positional encoding (fp32 in, bf16 out) ----------------
__global__ void Transformer_33792802685820_kernel(
    const int* __restrict__ x, const float* __restrict__ emb,
    const float* __restrict__ pe, u16* __restrict__ h) {
  const int t = blockIdx.x;          // token index 0..NTOK-1
  const int s = t & (S_DIM - 1);     // position within sequence
  const int row = x[t];
  const int d = threadIdx.x * 4;     // 256 threads * 4 = 1024 = D
  float4 e = *(const float4*)(emb + (long)row * D_DIM + d);
  float4 p = *(const float4*)(pe + (long)s * D_DIM + d);
  ushort4 o;
  o.x = f2b(e.x + p.x);
  o.y = f2b(e.y + p.y);
  o.z = f2b(e.z + p.z);
  o.w = f2b(e.w + p.w);
  *(ushort4*)(h + (long)t * D_DIM + d) = o;
}

// ---------------- transpose fp32 -> bf16: out[C][R] = in[R][C] ----------------
__global__ void transpose_f_kernel(
    const float* __restrict__ in, u16* __restrict__ out, int R, int C) {
  __shared__ float tile[32][33];
  const int c0 = blockIdx.x * 32, r0 = blockIdx.y * 32;
  const int tx = threadIdx.x, ty = threadIdx.y; // 32 x 8
  for (int i = ty; i < 32; i += 8)
    tile[i][tx] = in[(long)(r0 + i) * C + (c0 + tx)];
  __syncthreads();
  for (int i = ty; i < 32; i += 8)
    out[(long)(c0 + i) * R + (r0 + tx)] = f2b(tile[tx][i]);
}

// ---------------- transpose bf16 -> bf16, batched over z ----------------
__global__ void transpose_b_kernel(
    const u16* __restrict__ in, u16* __restrict__ out, int R, int C) {
  __shared__ u16 tile[32][33];
  const long zoff = (long)blockIdx.z * R * C;
  const int c0 = blockIdx.x * 32, r0 = blockIdx.y * 32;
  const int tx = threadIdx.x, ty = threadIdx.y; // 32 x 8
  for (int i = ty; i < 32; i += 8)
    tile[i][tx] = in[zoff + (long)(r0 + i) * C + (c0 + tx)];
  __syncthreads();
  for (int i = ty; i < 32; i += 8)
    out[zoff + (long)(c0 + i) * R + (r0 + tx)] = tile[tx][i];
}

// ---------------- legacy 128x128 MFMA GEMM (kept for PV) ----------------
template<bool RELU, bool BIAS, bool OUTF32>
__global__ void gemm_bt(
    const u16* __restrict__ A, const u16* __restrict__ Bt,
    const float* __restrict__ bias, u16* __restrict__ C, float* __restrict__ Cf,
    int M, int N, int K, float scale, long sA, long sB, long sC) {
  __shared__ u16 As[128 * 32];
  __shared__ u16 Bs[128 * 32];
  const int tid  = threadIdx.x;
  const int wave = tid >> 6;
  const int lane = tid & 63;
  const int quad = lane >> 4;
  const int l16  = lane & 15;
  const int wm = (wave & 1) << 6;
  const int wn = (wave >> 1) << 6;
  A  += (long)blockIdx.z * sA;
  Bt += (long)blockIdx.z * sB;
  const int m0 = blockIdx.y << 7;
  const int n0 = blockIdx.x << 7;

  const int row_a = tid >> 2;
  const int c4    = (tid & 3) << 3;
  const u16* gA = A  + (long)(m0 + row_a) * K + c4;
  const u16* gB = Bt + (long)(n0 + row_a) * K + c4;
  u16* lA = &As[tid * 8];
  u16* lB = &Bs[tid * 8];

  fx4 acc[4][4] = {};

  for (int k0 = 0; k0 < K; k0 += 32) {
    async16(lA,            gA + k0);
    async16(lA + 64 * 32,  gA + (long)64 * K + k0);
    async16(lB,            gB + k0);
    async16(lB + 64 * 32,  gB + (long)64 * K + k0);
    __syncthreads();
    short8 af[4], bfv[4];
    #pragma unroll
    for (int i = 0; i < 4; ++i) {
      af[i]  = *(const short8*)&As[(wm + i * 16 + l16) * 32 + quad * 8];
      bfv[i] = *(const short8*)&Bs[(wn + i * 16 + l16) * 32 + quad * 8];
    }
    __syncthreads();
    #pragma unroll
    for (int mi = 0; mi < 4; ++mi)
      #pragma unroll
      for (int ni = 0; ni < 4; ++ni)
        acc[mi][ni] = __builtin_amdgcn_mfma_f32_16x16x32_bf16(
            af[mi], bfv[ni], acc[mi][ni], 0, 0, 0);
  }

  float bv[4];
  #pragma unroll
  for (int ni = 0; ni < 4; ++ni)
    bv[ni] = BIAS ? bias[n0 + wn + ni * 16 + l16] : 0.0f;

  #pragma unroll
  for (int mi = 0; mi < 4; ++mi) {
    #pragma unroll
    for (int r = 0; r < 4; ++r) {
      const long row = m0 + wm + mi * 16 + quad * 4 + r;
      const long base = row * N + n0 + wn + l16;
      #pragma unroll
      for (int ni = 0; ni < 4; ++ni) {
        float v = acc[mi][ni][r] * scale + bv[ni];
        if (RELU) { if (v < 0.0f) v = 0.0f; }
        if (OUTF32) Cf[(long)blockIdx.z * sC + base + ni * 16] = v;
        else        C [(long)blockIdx.z * sC + base + ni * 16] = f2b(v);
      }
    }
  }
}

// ---------------- 256x256 8-phase MFMA GEMM (T1+T2+T3+T4+T5 port) ----------------
// C = act(scale*A@Bt^T + bias). A [M,K], Bt [N,K] bf16 row-major, M,N %256==0,
// K %64==0, nwg(x*y) %8==0. 512 threads = 8 waves (2M x 4N), per-wave 128x64 out.
// LDS: A,B double-buffered K-tiles [256][64] bf16 = 128 KiB total.
// Swizzle: 16B-chunk c_phys = c_log ^ (row&7)  (read side + pre-swizzled DMA source).
// Schedule per K-tile t (4 phases, raw barriers, counted vmcnt once per tile):
//   lp0 (ks0,mh0): rd 8,  stage B(t+1)h1   lp1 (ks0,mh1): rd 4, stage A(t+1)h0
//   lp2 (ks1,mh0): rd 8,  stage A(t+1)h1   lp3 (ks1,mh1): rd 4, stage B(t+2)h0
//   lp3 tail: s_waitcnt vmcnt(2) + barrier  -> tile t+1 fully landed before its reads.
// Every stage targets a region whose last reads are >=1 barrier behind (race-free).
template<bool RELU, bool BIAS, bool OUTF32>
__global__ __launch_bounds__(512, 2) void gemm256(
    const u16* __restrict__ A, const u16* __restrict__ Bt,
    const float* __restrict__ bias, u16* __restrict__ C, float* __restrict__ Cf,
    int M, int N, int K, float scale, long sA_, long sB_, long sC_) {
  __shared__ u16 sA[2][256 * 64];
  __shared__ u16 sB[2][256 * 64];
  const int tid  = threadIdx.x;
  const int lane = tid & 63;
  const int wave = tid >> 6;
  const int quad = lane >> 4;
  const int l16  = lane & 15;
  const int swz  = l16 & 7;
  const int wm   = wave >> 2;   // 0..1
  const int wn   = wave & 3;    // 0..3

  // T1: bijective XCD swizzle (nwg % 8 == 0 for all launches here)
  const int gx  = gridDim.x;
  const int nwg = gx * gridDim.y;
  const int id0 = blockIdx.y * gx + blockIdx.x;
  const int cpx = nwg >> 3;
  const int sid = (id0 & 7) * cpx + (id0 >> 3);
  const int n0  = (sid % gx) << 8;
  const int m0  = (sid / gx) << 8;

  A  += (long)blockIdx.z * sA_;
  Bt += (long)blockIdx.z * sB_;

  // staging: one issue = 512 thr x 16B = 64 rows x 64 k. src pre-swizzled (rule 21).
  const int srow = tid >> 3;                     // row within issue
  const int cl   = (tid & 7) ^ (srow & 7);       // logical k-chunk feeding this slot
  const u16* gA = A  + (long)(m0 + srow) * K + cl * 8;
  const u16* gB = Bt + (long)(n0 + srow) * K + cl * 8;
  const int ldst = tid * 8;                      // linear LDS dest (lane x 16B)

  fx4 acc[8][4] = {};
  short8 ar[4], br[4];

  const int NT = K >> 6;

#define STAGE_A(b, t, half) do { \
    const long ko_ = (long)(t) * 64; \
    async16(&sA[b][(half) * 8192 + ldst],        gA + (long)((half) * 128     ) * K + ko_); \
    async16(&sA[b][(half) * 8192 + 4096 + ldst], gA + (long)((half) * 128 + 64) * K + ko_); \
  } while (0)
#define STAGE_B(b, t, half) do { \
    const long ko_ = (long)(t) * 64; \
    async16(&sB[b][(half) * 8192 + ldst],        gB + (long)((half) * 128     ) * K + ko_); \
    async16(&sB[b][(half) * 8192 + 4096 + ldst], gB + (long)((half) * 128 + 64) * K + ko_); \
  } while (0)
#define RD_A(b, mh, ks) do { \
    _Pragma("unroll") for (int i_ = 0; i_ < 4; ++i_) { \
      const int row_ = wm * 128 + ((mh) * 4 + i_) * 16 + l16; \
      ar[i_] = *(const short8*)&sA[b][row_ * 64 + ((((ks) << 2) | quad) ^ swz) * 8]; \
    } } while (0)
#define RD_B(b, ks) do { \
    _Pragma("unroll") for (int n_ = 0; n_ < 4; ++n_) { \
      const int row_ = wn * 64 + n_ * 16 + l16; \
      br[n_] = *(const short8*)&sB[b][row_ * 64 + ((((ks) << 2) | quad) ^ swz) * 8]; \
    } } while (0)
#define MM(mh) do { \
    _Pragma("unroll") for (int i_ = 0; i_ < 4; ++i_) \
      _Pragma("unroll") for (int n_ = 0; n_ < 4; ++n_) \
        acc[(mh) * 4 + i_][n_] = __builtin_amdgcn_mfma_f32_16x16x32_bf16( \
            ar[i_], br[n_], acc[(mh) * 4 + i_][n_], 0, 0, 0); \
  } while (0)
#define MFMA_CLUSTER(mh) do { \
    __builtin_amdgcn_sched_barrier(0); \
    __builtin_amdgcn_s_setprio(1); \
    MM(mh); \
    __builtin_amdgcn_s_setprio(0); \
    __builtin_amdgcn_sched_barrier(0); \
  } while (0)

  // prologue: tile0 (4 halves) + B(1)h0; drain to 1 half outstanding; sync.
  STAGE_B(0, 0, 0); STAGE_B(0, 0, 1);
  STAGE_A(0, 0, 0); STAGE_A(0, 0, 1);
  STAGE_B(1, 1, 0);
  asm volatile("s_waitcnt vmcnt(2)" ::: "memory");
  BARR;

  for (int t = 0; t < NT; ++t) {
    const int b = t & 1, b1 = b ^ 1;
    // lp0: (ks0, mh0)
    RD_A(b, 0, 0); RD_B(b, 0);
    if (t + 1 < NT) STAGE_B(b1, t + 1, 1);
    BARR;
    MFMA_CLUSTER(0);
    BARR;
    // lp1: (ks0, mh1)
    RD_A(b, 1, 0);
    if (t + 1 < NT) STAGE_A(b1, t + 1, 0);
    BARR;
    MFMA_CLUSTER(1);
    BARR;
    // lp2: (ks1, mh0)
    RD_A(b, 0, 1); RD_B(b, 1);
    if (t + 1 < NT) STAGE_A(b1, t + 1, 1);
    BARR;
    MFMA_CLUSTER(0);
    BARR;
    // lp3: (ks1, mh1)
    RD_A(b, 1, 1);
    if (t + 2 < NT) STAGE_B(b, t + 2, 0);
    BARR;
    MFMA_CLUSTER(1);
    asm volatile("s_waitcnt vmcnt(2)" ::: "memory"); // tile t+1 landed (all waves after BARR)
    BARR;
  }

  // epilogue: C/D layout col=lane&15, row=quad*4+reg (verified m89/m91)
  float bv[4];
  #pragma unroll
  for (int n = 0; n < 4; ++n)
    bv[n] = BIAS ? bias[n0 + wn * 64 + n * 16 + l16] : 0.0f;

  #pragma unroll
  for (int f = 0; f < 8; ++f) {
    #pragma unroll
    for (int r = 0; r < 4; ++r) {
      const long row  = m0 + wm * 128 + f * 16 + quad * 4 + r;
      const long base = (long)blockIdx.z * sC_ + row * N + n0 + wn * 64 + l16;
      #pragma unroll
      for (int n = 0; n < 4; ++n) {
        float v = acc[f][n][r] * scale + bv[n];
        if (RELU) { if (v < 0.0f) v = 0.0f; }  // NaN-transparent ReLU
        if (OUTF32) Cf[base + n * 16] = v;
        else        C [base + n * 16] = f2b(v);
      }
    }
  }
#undef STAGE_A
#undef STAGE_B
#undef RD_A
#undef RD_B
#undef MM
#undef MFMA_CLUSTER
}

// ---------------- masked softmax over row (keys k >= q kept; triu mask) ----------------
__global__ void softmax_kernel(u16* __restrict__ P) {
  const int q = blockIdx.x;
  u16* p = P + ((long)blockIdx.y * S_DIM + q) * S_DIM;
  const int tid = threadIdx.x;
  const int wave = tid >> 6, lane = tid & 63;
  __shared__ float red[4];
  float vals[8];
  float mx = -3.0e38f;
  for (int it = 0; it < 8; ++it) {
    int k = tid + it * 256;
    float v = (k >= q) ? b2f(p[k]) : -3.0e38f;
    vals[it] = v;
    mx = fmaxf(mx, v);
  }
  for (int off = 32; off > 0; off >>= 1)
    mx = fmaxf(mx, __shfl_down(mx, off, 64));
  if (lane == 0) red[wave] = mx;
  __syncthreads();
  mx = fmaxf(fmaxf(red[0], red[1]), fmaxf(red[2], red[3]));
  __syncthreads();
  float sum = 0.0f;
  for (int it = 0; it < 8; ++it) {
    int k = tid + it * 256;
    float e = (k >= q) ? __expf(vals[it] - mx) : 0.0f;
    vals[it] = e;
    sum += e;
  }
  for (int off = 32; off > 0; off >>= 1)
    sum += __shfl_down(sum, off, 64);
  if (lane == 0) red[wave] = sum;
  __syncthreads();
  sum = red[0] + red[1] + red[2] + red[3];
  const float inv = 1.0f / sum;
  for (int it = 0; it < 8; ++it) {
    int k = tid + it * 256;
    p[k] = f2b(vals[it] * inv);
  }
}

extern "C" void kernel_launch(void* const* d_in, const int* in_sizes, int n_in,
                              void* d_out, int out_size, void* d_ws, size_t ws_size,
                              hipStream_t stream) {
  (void)in_sizes; (void)n_in; (void)out_size; (void)ws_size;
  const int*   x   = (const int*)d_in[0];
  const float* emb = (const float*)d_in[1];
  const float* pe  = (const float*)d_in[2];
  const float* wq  = (const float*)d_in[3];
  const float* bq  = (const float*)d_in[4];
  const float* wk  = (const float*)d_in[5];
  const float* bk  = (const float*)d_in[6];
  const float* wv  = (const float*)d_in[7];
  const float* bv  = (const float*)d_in[8];
  const float* w1s = (const float*)d_in[9];
  const float* b1s = (const float*)d_in[10];
  const float* w2s = (const float*)d_in[11];
  const float* b2s = (const float*)d_in[12];
  float* out = (float*)d_out;

  // workspace: bf16 internal activations/weights, ~124 MB.
  // aliases: vT <- q (q dead after scores); mb <- kx+v+P (dead after attention)
  u16* ws  = (u16*)d_ws;
  u16* h   = ws;                               // [8192,1024]
  u16* q   = h  + (long)NTOK * D_DIM;
  u16* kx  = q  + (long)NTOK * D_DIM;
  u16* v   = kx + (long)NTOK * D_DIM;
  u16* P   = v  + (long)NTOK * D_DIM;          // [4][2048,2048]
  u16* wqT = P  + (long)B_DIM * S_DIM * S_DIM; // [1024,1024]
  u16* wkT = wqT + (long)D_DIM * D_DIM;
  u16* wvT = wkT + (long)D_DIM * D_DIM;
  u16* w1T = wvT + (long)D_DIM * D_DIM;        // [4096,1024] per-layer
  u16* w2T = w1T + (long)D_DIM * M_DIM;        // [1024,4096] per-layer
  u16* vT  = q;                                // [4][1024,2048] aliases q
  u16* mb  = kx;                               // [8192,4096] aliases kx,v,P exactly

  const dim3 blk256(256);
  const dim3 blk512(512);
  const dim3 blkT(32, 8);

  // canary prefill of fp32 output (overwritten by final GEMM on success)
  canary_kernel<<<dim3(NTOK), blk256, 0, stream>>>(out);

  // QKV weight transposes (fp32 -> bf16 Bt layout)
  transpose_f_kernel<<<dim3(32, 32), blkT, 0, stream>>>(wq, wqT, 1024, 1024);
  transpose_f_kernel<<<dim3(32, 32), blkT, 0, stream>>>(wk, wkT, 1024, 1024);
  transpose_f_kernel<<<dim3(32, 32), blkT, 0, stream>>>(wv, wvT, 1024, 1024);

  // h = bf16(emb[x] + pos_enc)
  Transformer_33792802685820_kernel<<<dim3(NTOK), blk256, 0, stream>>>(x, emb, pe, h);

  // q,k,v projections (M=8192, N=1024, K=1024) — 256^2 8-phase GEMM
  gemm256<false, true, false><<<dim3(4, 32, 1), blk512, 0, stream>>>(h, wqT, bq, q,  nullptr, NTOK, D_DIM, D_DIM, 1.0f, 0, 0, 0);
  gemm256<false, true, false><<<dim3(4, 32, 1), blk512, 0, stream>>>(h, wkT, bk, kx, nullptr, NTOK, D_DIM, D_DIM, 1.0f, 0, 0, 0);
  gemm256<false, true, false><<<dim3(4, 32, 1), blk512, 0, stream>>>(h, wvT, bv, v,  nullptr, NTOK, D_DIM, D_DIM, 1.0f, 0, 0, 0);

  // scores = (Q @ K^T) / sqrt(D); K already [key,d] = Bt layout
  gemm256<false, false, false><<<dim3(8, 8, 4), blk512, 0, stream>>>(q, kx, nullptr, P, nullptr,
      S_DIM, S_DIM, D_DIM, 0.03125f, (long)S_DIM * D_DIM, (long)S_DIM * D_DIM, (long)S_DIM * S_DIM);

  // softmax with triu (self+future) mask, in place
  softmax_kernel<<<dim3(S_DIM, B_DIM), blk256, 0, stream>>>(P);

  // V^T per batch (into dead q), then attn_out = relu(P @ V) — legacy 128^2 GEMM
  // (256^2 grid would be 128 wgs = half-idle; legacy 512-wg kernel is equal/better here)
  transpose_b_kernel<<<dim3(32, 64, 4), blkT, 0, stream>>>(v, vT, 2048, 1024);
  gemm_bt<true, false, false><<<dim3(8, 16, 4), blk256, 0, stream>>>(P, vT, nullptr, h, nullptr,
      S_DIM, D_DIM, S_DIM, 1.0f, (long)S_DIM * S_DIM, (long)D_DIM * S_DIM, (long)S_DIM * D_DIM);

  // FFN stack; weights transposed per layer (fp32 -> bf16)
  for (int i = 0; i < 4; ++i) {
    transpose_f_kernel<<<dim3(128, 32), blkT, 0, stream>>>(w1s + (long)i * D_DIM * M_DIM, w1T, 1024, 4096);
    transpose_f_kernel<<<dim3(32, 128), blkT, 0, stream>>>(w2s + (long)i * D_DIM * M_DIM, w2T, 4096, 1024);
    gemm256<true, true, false><<<dim3(16, 32, 1), blk512, 0, stream>>>(
        h, w1T, b1s + i * M_DIM, mb, nullptr, NTOK, M_DIM, D_DIM, 1.0f, 0, 0, 0);
    if (i == 3)
      gemm256<true, true, true><<<dim3(4, 32, 1), blk512, 0, stream>>>(
          mb, w2T, b2s + i * D_DIM, nullptr, out, NTOK, D_DIM, M_DIM, 1.0f, 0, 0, 0);
    else
      gemm256<true, true, false><<<dim3(4, 32, 1), blk512, 0, stream>>>(
          mb, w2T, b2s + i * D_DIM, h, nullptr, NTOK, D_DIM, M_DIM, 1.0f, 0, 0, 0);
  }
}

// Round 3
// 1239.908 us; speedup vs baseline: 1.0125x; 1.0125x over previous
//
#include <hip/hip_runtime.h>

// Shapes (fixed for this problem)
#define D_DIM 1024
#define S_DIM 2048
#define B_DIM 4
#define M_DIM 4096
#define NTOK  8192   // B*S

typedef unsigned short u16;
typedef __attribute__((ext_vector_type(8))) short short8;  // 8 bf16 (guide-verified frag type)
typedef __attribute__((ext_vector_type(4))) float fx4;

static __device__ __forceinline__ float b2f(u16 u) {
  union { unsigned int i; float f; } v; v.i = ((unsigned int)u) << 16; return v.f;
}
static __device__ __forceinline__ u16 f2b(float f) {
  union { float f; unsigned int i; } v; v.f = f;
  unsigned int r = v.i + 0x7fffu + ((v.i >> 16) & 1u); // RNE
  return (u16)(r >> 16);
}
// async global->LDS DMA, 16B per lane
static __device__ __forceinline__ void async16(u16* lds, const u16* g) {
  __builtin_amdgcn_global_load_lds(
      (__attribute__((address_space(1))) void*)(u16*)g,
      (__attribute__((address_space(3))) void*)lds, 16, 0, 0);
}

// ---------------- canary: prefill fp32 output with 1.0 (diagnostic) ----------------
__global__ void canary_kernel(float* __restrict__ out) {
  const long i = ((long)blockIdx.x * 256 + threadIdx.x) * 4;
  float4 v = {1.0f, 1.0f, 1.0f, 1.0f};
  *(float4*)(out + i) = v;
}

// ---------------- embedding gather + positional encoding (fp32 in, bf16 out) ----------------
__global__ void Transformer_33792802685820_kernel(
    const int* __restrict__ x, const float* __restrict__ emb,
    const float* __restrict__ pe, u16* __restrict__ h) {
  const int t = blockIdx.x;          // token index 0..NTOK-1
  const int s = t & (S_DIM - 1);     // position within sequence
  const int row = x[t];
  const int d = threadIdx.x * 4;     // 256 threads * 4 = 1024 = D
  float4 e = *(const float4*)(emb + (long)row * D_DIM + d);
  float4 p = *(const float4*)(pe + (long)s * D_DIM + d);
  ushort4 o;
  o.x = f2b(e.x + p.x);
  o.y = f2b(e.y + p.y);
  o.z = f2b(e.z + p.z);
  o.w = f2b(e.w + p.w);
  *(ushort4*)(h + (long)t * D_DIM + d) = o;
}

// ---------------- transpose fp32 -> bf16: out[C][R] = in[R][C] ----------------
__global__ void transpose_f_kernel(
    const float* __restrict__ in, u16* __restrict__ out, int R, int C) {
  __shared__ float tile[32][33];
  const int c0 = blockIdx.x * 32, r0 = blockIdx.y * 32;
  const int tx = threadIdx.x, ty = threadIdx.y; // 32 x 8
  for (int i = ty; i < 32; i += 8)
    tile[i][tx] = in[(long)(r0 + i) * C + (c0 + tx)];
  __syncthreads();
  for (int i = ty; i < 32; i += 8)
    out[(long)(c0 + i) * R + (r0 + tx)] = f2b(tile[tx][i]);
}

// ---------------- transpose bf16 -> bf16, batched over z ----------------
__global__ void transpose_b_kernel(
    const u16* __restrict__ in, u16* __restrict__ out, int R, int C) {
  __shared__ u16 tile[32][33];
  const long zoff = (long)blockIdx.z * R * C;
  const int c0 = blockIdx.x * 32, r0 = blockIdx.y * 32;
  const int tx = threadIdx.x, ty = threadIdx.y; // 32 x 8
  for (int i = ty; i < 32; i += 8)
    tile[i][tx] = in[zoff + (long)(r0 + i) * C + (c0 + tx)];
  __syncthreads();
  for (int i = ty; i < 32; i += 8)
    out[zoff + (long)(c0 + i) * R + (r0 + tx)] = tile[tx][i];
}

// ---------------- legacy 128x128 MFMA GEMM (N=1024 GEMMs: full-grid occupancy) ----------------
template<bool RELU, bool BIAS, bool OUTF32>
__global__ void gemm_bt(
    const u16* __restrict__ A, const u16* __restrict__ Bt,
    const float* __restrict__ bias, u16* __restrict__ C, float* __restrict__ Cf,
    int M, int N, int K, float scale, long sA, long sB, long sC) {
  __shared__ u16 As[128 * 32];
  __shared__ u16 Bs[128 * 32];
  const int tid  = threadIdx.x;
  const int wave = tid >> 6;
  const int lane = tid & 63;
  const int quad = lane >> 4;
  const int l16  = lane & 15;
  const int wm = (wave & 1) << 6;
  const int wn = (wave >> 1) << 6;
  A  += (long)blockIdx.z * sA;
  Bt += (long)blockIdx.z * sB;
  const int m0 = blockIdx.y << 7;
  const int n0 = blockIdx.x << 7;

  const int row_a = tid >> 2;
  const int c4    = (tid & 3) << 3;
  const u16* gA = A  + (long)(m0 + row_a) * K + c4;
  const u16* gB = Bt + (long)(n0 + row_a) * K + c4;
  u16* lA = &As[tid * 8];
  u16* lB = &Bs[tid * 8];

  fx4 acc[4][4] = {};

  for (int k0 = 0; k0 < K; k0 += 32) {
    async16(lA,            gA + k0);
    async16(lA + 64 * 32,  gA + (long)64 * K + k0);
    async16(lB,            gB + k0);
    async16(lB + 64 * 32,  gB + (long)64 * K + k0);
    __syncthreads();
    short8 af[4], bfv[4];
    #pragma unroll
    for (int i = 0; i < 4; ++i) {
      af[i]  = *(const short8*)&As[(wm + i * 16 + l16) * 32 + quad * 8];
      bfv[i] = *(const short8*)&Bs[(wn + i * 16 + l16) * 32 + quad * 8];
    }
    __syncthreads();
    #pragma unroll
    for (int mi = 0; mi < 4; ++mi)
      #pragma unroll
      for (int ni = 0; ni < 4; ++ni)
        acc[mi][ni] = __builtin_amdgcn_mfma_f32_16x16x32_bf16(
            af[mi], bfv[ni], acc[mi][ni], 0, 0, 0);
  }

  float bv[4];
  #pragma unroll
  for (int ni = 0; ni < 4; ++ni)
    bv[ni] = BIAS ? bias[n0 + wn + ni * 16 + l16] : 0.0f;

  #pragma unroll
  for (int mi = 0; mi < 4; ++mi) {
    #pragma unroll
    for (int r = 0; r < 4; ++r) {
      const long row = m0 + wm + mi * 16 + quad * 4 + r;
      const long base = row * N + n0 + wn + l16;
      #pragma unroll
      for (int ni = 0; ni < 4; ++ni) {
        float v = acc[mi][ni][r] * scale + bv[ni];
        if (RELU) { if (v < 0.0f) v = 0.0f; }
        if (OUTF32) Cf[(long)blockIdx.z * sC + base + ni * 16] = v;
        else        C [(long)blockIdx.z * sC + base + ni * 16] = f2b(v);
      }
    }
  }
}

// ---------------- 256x256 8-phase MFMA GEMM, retirement-ordered deep pipeline ----------------
// C = act(scale*A@Bt^T + bias). A [M,K], Bt [N,K] bf16 row-major; M,N %256==0,
// K %64==0, NT=K/64 >= 2, nwg %8==0. 512 thr = 8 waves (2M x 4N), 128x64 out/wave.
// LDS units (per buffer): A(mh,ks) = [128][32] bf16 = 1 DMA issue (rows {mh*64..+63} u
// {128+mh*64..+63}), B(ks) = [256][32] = 2 issues. 64 KiB/tile, double-buffered = 128 KiB.
// Swizzle: 16B-chunk phys = log ^ (lrow&3); DMA source pre-swizzled, reads XOR (rule 21).
// Phase q=(ks<<1|mh): ds_read A(mh,ks) [+B(ks) if mh==0]; 2 stage issues ordered by
// retirement of the unit being overwritten; barrier; setprio MFMA x16; barrier.
// Tile t+1 fully issued by t.ph0 => single bare vmcnt(6) at t.ph3 (6 = stages of ph1-3
// still in flight). Every load gets >=3 phases (~1500cyc) to land. No memory-clobber
// asm anywhere in the loop (a clobbered asm point re-inserts the vmcnt(0) drain).
template<bool RELU, bool BIAS, bool OUTF32>
__global__ __launch_bounds__(512) void gemm256(
    const u16* __restrict__ A, const u16* __restrict__ Bt,
    const float* __restrict__ bias, u16* __restrict__ C, float* __restrict__ Cf,
    int M, int N, int K, float scale, long sA_, long sB_, long sC_) {
  __shared__ u16 sA[2][16384];
  __shared__ u16 sB[2][16384];
  const int tid  = threadIdx.x;
  const int lane = tid & 63;
  const int wave = tid >> 6;
  const int quad = lane >> 4;
  const int l16  = lane & 15;
  const int wm   = wave >> 2;   // 0..1
  const int wn   = wave & 3;    // 0..3

  // T1: bijective XCD swizzle (nwg % 8 == 0 for all launches here)
  const int gx  = gridDim.x;
  const int nwg = gx * gridDim.y;
  const int id0 = blockIdx.y * gx + blockIdx.x;
  const int cpx = nwg >> 3;
  const int sid = (id0 & 7) * cpx + (id0 >> 3);
  const int n0  = (sid % gx) << 8;
  const int m0  = (sid / gx) << 8;

  A  += (long)blockIdx.z * sA_;
  Bt += (long)blockIdx.z * sB_;

  // per-thread staging source (pre-swizzled chunk, rule 21)
  const int lr   = tid >> 2;                    // unit-local row 0..127
  const int pc   = tid & 3;                     // physical 16B chunk
  const int lc   = pc ^ (lr & 3);               // logical chunk at this slot
  const int arow = (lr & 63) + ((lr >> 6) << 7);// A unit row -> tile row (pre mh*64)
  const u16* gA0 = A  + (long)(m0 + arow) * K + lc * 8;
  const u16* gB0 = Bt + (long)(n0 + lr)   * K + lc * 8;
  const int ldst = tid << 3;                    // linear LDS dest, 16B per lane

  // read-side swizzled chunk offset (lrow&3 == l16&3 for all our rows)
  const int rdo = (quad ^ (l16 & 3)) << 3;
  const int raA = wm * 64 + l16;                // + i*16 per frag
  const int raB = wn * 64 + l16;                // + n*16 per frag

  fx4 acc[8][4] = {};
  short8 ar[4], br[4];

  const int NT = K >> 6;

#define STG_A(b, t, mh, ks) \
  async16(&sA[b][((((ks) << 1) | (mh)) << 12) + ldst], \
          gA0 + (long)(mh) * 64 * K + (long)(t) * 64 + (ks) * 32)
#define STG_B1(b, t, ks) \
  async16(&sB[b][((ks) << 13) + ldst], gB0 + (long)(t) * 64 + (ks) * 32)
#define STG_B2(b, t, ks) \
  async16(&sB[b][((ks) << 13) + 4096 + ldst], \
          gB0 + (long)128 * K + (long)(t) * 64 + (ks) * 32)
#define RD_A(b, mh, ks) do { \
    _Pragma("unroll") for (int i_ = 0; i_ < 4; ++i_) \
      ar[i_] = *(const short8*)&sA[b][((((ks) << 1) | (mh)) << 12) + (raA + i_ * 16) * 32 + rdo]; \
  } while (0)
#define RD_B(b, ks) do { \
    _Pragma("unroll") for (int n_ = 0; n_ < 4; ++n_) \
      br[n_] = *(const short8*)&sB[b][((ks) << 13) + (raB + n_ * 16) * 32 + rdo]; \
  } while (0)
#define PRIO_MM(mh) do { \
    __builtin_amdgcn_s_setprio(1); \
    _Pragma("unroll") for (int i_ = 0; i_ < 4; ++i_) \
      _Pragma("unroll") for (int n_ = 0; n_ < 4; ++n_) \
        acc[(mh) * 4 + i_][n_] = __builtin_amdgcn_mfma_f32_16x16x32_bf16( \
            ar[i_], br[n_], acc[(mh) * 4 + i_][n_], 0, 0, 0); \
    __builtin_amdgcn_s_setprio(0); \
  } while (0)
#define SBAR  __builtin_amdgcn_s_barrier()
#define SCHED __builtin_amdgcn_sched_barrier(0)

  // prologue: tile0 all 8 issues (buf 0) + tile1 first 6 (buf 1); drain tile0; sync.
  STG_A(0, 0, 0, 0); STG_B1(0, 0, 0); STG_B2(0, 0, 0); STG_A(0, 0, 1, 0);
  STG_A(0, 0, 0, 1); STG_B1(0, 0, 1); STG_B2(0, 0, 1); STG_A(0, 0, 1, 1);
  STG_A(1, 1, 0, 0); STG_B1(1, 1, 0); STG_B2(1, 1, 0); STG_A(1, 1, 1, 0);
  STG_A(1, 1, 0, 1); STG_B1(1, 1, 1);
  asm volatile("s_waitcnt vmcnt(6)");
  SCHED;
  SBAR;

  for (int t = 0; t < NT; ++t) {
    const int b = t & 1, b1 = b ^ 1;
    // ph0 (mh0,ks0): stage last-2 units of tile t+1 (their t-1 reads retired)
    RD_A(b, 0, 0); RD_B(b, 0);
    if (t + 1 < NT) { STG_B2(b1, t + 1, 1); STG_A(b1, t + 1, 1, 1); }
    SBAR;
    PRIO_MM(0);
    SBAR; SCHED;
    // ph1 (mh1,ks0): stage A(0,0),B(0)a of t+2 (retired at ph0)
    RD_A(b, 1, 0);
    if (t + 2 < NT) { STG_A(b, t + 2, 0, 0); STG_B1(b, t + 2, 0); }
    SBAR;
    PRIO_MM(1);
    SBAR; SCHED;
    // ph2 (mh0,ks1): stage B(0)b,A(1,0) of t+2 (retired at ph0/ph1)
    RD_A(b, 0, 1); RD_B(b, 1);
    if (t + 2 < NT) { STG_B2(b, t + 2, 0); STG_A(b, t + 2, 1, 0); }
    SBAR;
    PRIO_MM(0);
    SBAR; SCHED;
    // ph3 (mh1,ks1): stage A(0,1),B(1)a of t+2 (retired at ph2); counted drain
    RD_A(b, 1, 1);
    if (t + 2 < NT) { STG_A(b, t + 2, 0, 1); STG_B1(b, t + 2, 1); }
    SBAR;
    PRIO_MM(1);
    if (t + 2 < NT) asm volatile("s_waitcnt vmcnt(6)");
    else            asm volatile("s_waitcnt vmcnt(0)");
    SCHED;
    SBAR; SCHED;
  }

  // epilogue: C/D layout col=lane&15, row=quad*4+reg (verified m89/m91)
  float bv[4];
  #pragma unroll
  for (int n = 0; n < 4; ++n)
    bv[n] = BIAS ? bias[n0 + wn * 64 + n * 16 + l16] : 0.0f;

  #pragma unroll
  for (int f = 0; f < 8; ++f) {
    #pragma unroll
    for (int r = 0; r < 4; ++r) {
      const long row  = m0 + wm * 128 + f * 16 + quad * 4 + r;
      const long base = (long)blockIdx.z * sC_ + row * N + n0 + wn * 64 + l16;
      #pragma unroll
      for (int n = 0; n < 4; ++n) {
        float v = acc[f][n][r] * scale + bv[n];
        if (RELU) { if (v < 0.0f) v = 0.0f; }  // NaN-transparent ReLU
        if (OUTF32) Cf[base + n * 16] = v;
        else        C [base + n * 16] = f2b(v);
      }
    }
  }
#undef STG_A
#undef STG_B1
#undef STG_B2
#undef RD_A
#undef RD_B
#undef PRIO_MM
#undef SBAR
#undef SCHED
}

// ---------------- masked softmax over row (keys k >= q kept; triu mask) ----------------
__global__ void softmax_kernel(u16* __restrict__ P) {
  const int q = blockIdx.x;
  u16* p = P + ((long)blockIdx.y * S_DIM + q) * S_DIM;
  const int tid = threadIdx.x;
  const int wave = tid >> 6, lane = tid & 63;
  __shared__ float red[4];
  float vals[8];
  float mx = -3.0e38f;
  for (int it = 0; it < 8; ++it) {
    int k = tid + it * 256;
    float v = (k >= q) ? b2f(p[k]) : -3.0e38f;
    vals[it] = v;
    mx = fmaxf(mx, v);
  }
  for (int off = 32; off > 0; off >>= 1)
    mx = fmaxf(mx, __shfl_down(mx, off, 64));
  if (lane == 0) red[wave] = mx;
  __syncthreads();
  mx = fmaxf(fmaxf(red[0], red[1]), fmaxf(red[2], red[3]));
  __syncthreads();
  float sum = 0.0f;
  for (int it = 0; it < 8; ++it) {
    int k = tid + it * 256;
    float e = (k >= q) ? __expf(vals[it] - mx) : 0.0f;
    vals[it] = e;
    sum += e;
  }
  for (int off = 32; off > 0; off >>= 1)
    sum += __shfl_down(sum, off, 64);
  if (lane == 0) red[wave] = sum;
  __syncthreads();
  sum = red[0] + red[1] + red[2] + red[3];
  const float inv = 1.0f / sum;
  for (int it = 0; it < 8; ++it) {
    int k = tid + it * 256;
    p[k] = f2b(vals[it] * inv);
  }
}

extern "C" void kernel_launch(void* const* d_in, const int* in_sizes, int n_in,
                              void* d_out, int out_size, void* d_ws, size_t ws_size,
                              hipStream_t stream) {
  (void)in_sizes; (void)n_in; (void)out_size; (void)ws_size;
  const int*   x   = (const int*)d_in[0];
  const float* emb = (const float*)d_in[1];
  const float* pe  = (const float*)d_in[2];
  const float* wq  = (const float*)d_in[3];
  const float* bq  = (const float*)d_in[4];
  const float* wk  = (const float*)d_in[5];
  const float* bk  = (const float*)d_in[6];
  const float* wv  = (const float*)d_in[7];
  const float* bv  = (const float*)d_in[8];
  const float* w1s = (const float*)d_in[9];
  const float* b1s = (const float*)d_in[10];
  const float* w2s = (const float*)d_in[11];
  const float* b2s = (const float*)d_in[12];
  float* out = (float*)d_out;

  // workspace: bf16 internal activations/weights, ~124 MB.
  // aliases: vT <- q (q dead after scores); mb <- kx+v+P (dead after attention)
  u16* ws  = (u16*)d_ws;
  u16* h   = ws;                               // [8192,1024]
  u16* q   = h  + (long)NTOK * D_DIM;
  u16* kx  = q  + (long)NTOK * D_DIM;
  u16* v   = kx + (long)NTOK * D_DIM;
  u16* P   = v  + (long)NTOK * D_DIM;          // [4][2048,2048]
  u16* wqT = P  + (long)B_DIM * S_DIM * S_DIM; // [1024,1024]
  u16* wkT = wqT + (long)D_DIM * D_DIM;
  u16* wvT = wkT + (long)D_DIM * D_DIM;
  u16* w1T = wvT + (long)D_DIM * D_DIM;        // [4096,1024] per-layer
  u16* w2T = w1T + (long)D_DIM * M_DIM;        // [1024,4096] per-layer
  u16* vT  = q;                                // [4][1024,2048] aliases q
  u16* mb  = kx;                               // [8192,4096] aliases kx,v,P exactly

  const dim3 blk256(256);
  const dim3 blk512(512);
  const dim3 blkT(32, 8);

  // canary prefill of fp32 output (overwritten by final GEMM on success)
  canary_kernel<<<dim3(NTOK), blk256, 0, stream>>>(out);

  // QKV weight transposes (fp32 -> bf16 Bt layout)
  transpose_f_kernel<<<dim3(32, 32), blkT, 0, stream>>>(wq, wqT, 1024, 1024);
  transpose_f_kernel<<<dim3(32, 32), blkT, 0, stream>>>(wk, wkT, 1024, 1024);
  transpose_f_kernel<<<dim3(32, 32), blkT, 0, stream>>>(wv, wvT, 1024, 1024);

  // h = bf16(emb[x] + pos_enc)
  Transformer_33792802685820_kernel<<<dim3(NTOK), blk256, 0, stream>>>(x, emb, pe, h);

  // q,k,v projections (M=8192, N=1024, K=1024) — legacy (512 wgs = full grid;
  // gemm256 grid would be 128 wgs = half the CUs idle)
  gemm_bt<false, true, false><<<dim3(8, 64, 1), blk256, 0, stream>>>(h, wqT, bq, q,  nullptr, NTOK, D_DIM, D_DIM, 1.0f, 0, 0, 0);
  gemm_bt<false, true, false><<<dim3(8, 64, 1), blk256, 0, stream>>>(h, wkT, bk, kx, nullptr, NTOK, D_DIM, D_DIM, 1.0f, 0, 0, 0);
  gemm_bt<false, true, false><<<dim3(8, 64, 1), blk256, 0, stream>>>(h, wvT, bv, v,  nullptr, NTOK, D_DIM, D_DIM, 1.0f, 0, 0, 0);

  // scores = (Q @ K^T) / sqrt(D); K already [key,d] = Bt layout (256 wgs = full grid)
  gemm256<false, false, false><<<dim3(8, 8, 4), blk512, 0, stream>>>(q, kx, nullptr, P, nullptr,
      S_DIM, S_DIM, D_DIM, 0.03125f, (long)S_DIM * D_DIM, (long)S_DIM * D_DIM, (long)S_DIM * S_DIM);

  // softmax with triu (self+future) mask, in place
  softmax_kernel<<<dim3(S_DIM, B_DIM), blk256, 0, stream>>>(P);

  // V^T per batch (into dead q), then attn_out = relu(P @ V) — legacy
  transpose_b_kernel<<<dim3(32, 64, 4), blkT, 0, stream>>>(v, vT, 2048, 1024);
  gemm_bt<true, false, false><<<dim3(8, 16, 4), blk256, 0, stream>>>(P, vT, nullptr, h, nullptr,
      S_DIM, D_DIM, S_DIM, 1.0f, (long)S_DIM * S_DIM, (long)D_DIM * S_DIM, (long)S_DIM * D_DIM);

  // FFN stack; weights transposed per layer (fp32 -> bf16)
  for (int i = 0; i < 4; ++i) {
    transpose_f_kernel<<<dim3(128, 32), blkT, 0, stream>>>(w1s + (long)i * D_DIM * M_DIM, w1T, 1024, 4096);
    transpose_f_kernel<<<dim3(32, 128), blkT, 0, stream>>>(w2s + (long)i * D_DIM * M_DIM, w2T, 4096, 1024);
    // w1: N=4096 -> gemm256 (512 wgs = full grid)
    gemm256<true, true, false><<<dim3(16, 32, 1), blk512, 0, stream>>>(
        h, w1T, b1s + i * M_DIM, mb, nullptr, NTOK, M_DIM, D_DIM, 1.0f, 0, 0, 0);
    // w2: N=1024 -> legacy (512 wgs)
    if (i == 3)
      gemm_bt<true, true, true><<<dim3(8, 64, 1), blk256, 0, stream>>>(
          mb, w2T, b2s + i * D_DIM, nullptr, out, NTOK, D_DIM, M_DIM, 1.0f, 0, 0, 0);
    else
      gemm_bt<true, true, false><<<dim3(8, 64, 1), blk256, 0, stream>>>(
          mb, w2T, b2s + i * D_DIM, h, nullptr, NTOK, D_DIM, M_DIM, 1.0f, 0, 0, 0);
  }
}